// Round 4
// baseline (360.869 us; speedup 1.0000x reference)
//
#include <hip/hip_runtime.h>
#include <cstdint>
#include <cstddef>

#define BATCH 8192
#define DIN   1025
#define HID   1024
#define NACT  1026
#define NHEAD 513
#define KSEL  32
#define KP0   1088   /* DIN padded to multiple of 64 */
#define LGN   1024   /* logits cols 0..1023 via GEMM; 1024/1025 computed in sample */
#define GRIDM 512    /* k_mlp grid: 64 mtiles x 8 ntiles */

typedef unsigned short u16;
typedef short bf16x8 __attribute__((ext_vector_type(8)));
typedef float f32x4 __attribute__((ext_vector_type(4)));

__device__ __forceinline__ u16 f2bf(float f) {
  unsigned u = __float_as_uint(f);
  u += 0x7fff + ((u >> 16) & 1);   // round-to-nearest-even
  return (u16)(u >> 16);
}
__device__ __forceinline__ float bf2f(u16 h) {
  return __uint_as_float((unsigned)h << 16);
}

__device__ __forceinline__ void async_cp16(const u16* g, u16* l) {
  __builtin_amdgcn_global_load_lds((const __attribute__((address_space(1))) void*)g,
                                   (__attribute__((address_space(3))) void*)l,
                                   16, 0, 0);
}

// device-scope grid barrier (all GRIDM blocks co-resident: LDS 64KB -> 2/CU,
// grid = 2x256CU exactly). Protocol: __syncthreads drains each wave's stores
// (vmcnt0), tid0 release-fence (agent: L2 writeback) + atomic arrive, spin
// acquire, acquire-fence (L1/L2 inv), __syncthreads. Counters one-shot per
// launch, zeroed by k_cvt (prior kernel on stream).
__device__ __forceinline__ void grid_sync(unsigned* ctr) {
  __syncthreads();
  if (threadIdx.x == 0) {
    __threadfence();
    __hip_atomic_fetch_add(ctr, 1u, __ATOMIC_ACQ_REL, __HIP_MEMORY_SCOPE_AGENT);
    while (__hip_atomic_load(ctr, __ATOMIC_ACQUIRE, __HIP_MEMORY_SCOPE_AGENT) < (unsigned)GRIDM)
      __builtin_amdgcn_s_sleep(2);
    __threadfence();
  }
  __syncthreads();
}

// ---------------- conversion kernel (512 thr, grid 4352) ----------------
// blocks: state cvt one pass (4352*512*4 = BATCH*KP0); blocks 0..3136 also do one
// 32x32 weight-transpose tile each (W0t 1088, W1t 1024, W2t 1024, W2c 1).
// block 4351 additionally zeroes the grid-barrier counters for k_mlp.
__global__ __launch_bounds__(512) void k_cvt(const float* __restrict__ state,
    const float* __restrict__ W0, const float* __restrict__ W1,
    const float* __restrict__ W2,
    u16* __restrict__ As, u16* __restrict__ W0t, u16* __restrict__ W1t,
    u16* __restrict__ W2t, u16* __restrict__ W2c, unsigned* __restrict__ gbar) {
  const int tid = threadIdx.x;
  const int b = blockIdx.x;
  // state f32 [B][DIN] -> bf16 [B][KP0], 4 elems/thread
  {
    int i = b * 512 + tid;
    const int QPR = KP0 / 4;   // 272
    int r = i / QPR, c4 = (i - r * QPR) * 4;
    const float* src = state + (size_t)r * DIN + c4;
    ushort4 o;
    if (c4 + 3 < DIN) {
      o.x = f2bf(src[0]); o.y = f2bf(src[1]); o.z = f2bf(src[2]); o.w = f2bf(src[3]);
    } else {
      o.x = (c4 + 0 < DIN) ? f2bf(src[0]) : 0;
      o.y = (c4 + 1 < DIN) ? f2bf(src[1]) : 0;
      o.z = (c4 + 2 < DIN) ? f2bf(src[2]) : 0;
      o.w = (c4 + 3 < DIN) ? f2bf(src[3]) : 0;
    }
    *(ushort4*)(As + (size_t)r * KP0 + c4) = o;
  }
  if (b == 4351 && tid < 8) gbar[tid] = 0;
  if (b >= 3137) return;
  if (b == 3136) {   // W2 cols 1024,1025 -> W2c[2][1024]
    for (int e = tid; e < 2048; e += 512) {
      int j = e >> 10, k = e & 1023;
      W2c[e] = f2bf(W2[(size_t)k * NACT + 1024 + j]);
    }
    return;
  }
  const float* W; u16* Wt; int K, ldW, Kp, tt = b;
  if (tt < 1088)      { W = W0; Wt = W0t; K = DIN; ldW = HID;  Kp = KP0; }
  else if (tt < 2112) { tt -= 1088; W = W1; Wt = W1t; K = HID; ldW = HID;  Kp = HID; }
  else                { tt -= 2112; W = W2; Wt = W2t; K = HID; ldW = NACT; Kp = HID; }
  int n0 = (tt & 31) * 32, k0 = (tt >> 5) * 32;
  __shared__ float tile[32][33];
  const int tx = tid & 31, ty = tid >> 5;   // ty 0..15
#pragma unroll
  for (int i = 0; i < 32; i += 16) {
    int k = k0 + ty + i;
    tile[ty + i][tx] = (k < K) ? W[(size_t)k * ldW + n0 + tx] : 0.f;
  }
  __syncthreads();
#pragma unroll
  for (int i = 0; i < 32; i += 16)
    Wt[(size_t)(n0 + ty + i) * Kp + k0 + tx] = f2bf(tile[tx][ty + i]);
}

// ---- fused 3-layer MLP: persistent GEMM, grid 512 x 256 thr, grid_sync between
// layers. Inner loop identical to r3's verified gemm_bt (128x128 tile, BK=64,
// 2 blocks/CU, counted vmcnt(8), full 3-bit XOR bank swizzle, dbuf 2x32KB LDS).
// Fusion removes 2 launch gaps and makes the GEMM phase one >41us dispatch so
// rocprof's top-5 finally shows its MfmaUtil/VALUBusy/LDS_CONFLICT/Occupancy.
__global__ __launch_bounds__(256, 2)
void k_mlp(const u16* __restrict__ As, const u16* __restrict__ W0t,
           const float* __restrict__ b0, u16* __restrict__ h1,
           const u16* __restrict__ W1t, const float* __restrict__ b1,
           u16* __restrict__ h2,
           const u16* __restrict__ W2t, const float* __restrict__ b2v,
           u16* __restrict__ lgts, unsigned* __restrict__ gbar)
{
  __shared__ __align__(16) u16 lds[32768];   // 2 bufs x (A 8192 + B 8192 u16) = 64 KB

  const int d     = blockIdx.x;
  const int m8    = d & 7;
  const int ntile = (d >> 3) & 7;
  const int mtile = ((d >> 6) << 3) | m8;
  const size_t bm = (size_t)mtile * 128;
  const size_t bn = (size_t)ntile * 128;

  const int tid  = threadIdx.x;
  const int wave = tid >> 6;
  const int lane = tid & 63;
  const int waveM = wave >> 1, waveN = wave & 1;   // 2 x 2 waves, 64x64 each
  const int lr = lane & 15, lq = lane >> 4;

  // staging map (verified r3): chunk c -> row c>>3, slot c&7, kchunk g = slot^(row&7);
  // per-thread constants.
  const int row0 = tid >> 3;                       // 0..31
  const int g_   = (tid & 7) ^ ((tid >> 3) & 7);
  u16* lA = lds + wave * 512;          // + 2048*k per chunk; +buf*16384
  u16* lB = lds + 8192 + wave * 512;

  // fragment read map (verified r3)
  const int xr  = lane & 7;
  const int sk0 = ((0 | lq) ^ xr) * 8;   // kk=0
  const int sk1 = ((4 | lq) ^ xr) * 8;   // kk=1
  const u16* pa = lds + (waveM * 64 + lr) * 64;
  const u16* pb = lds + 8192 + (waveN * 64 + lr) * 64;

  for (int layer = 0; layer < 3; ++layer) {
    const u16 *A, *Bt; const float* bias; u16* C; int K, ldc, relu;
    if (layer == 0)      { A = As; Bt = W0t; bias = b0;  C = h1;   K = KP0; ldc = HID; relu = 1; }
    else if (layer == 1) { A = h1; Bt = W1t; bias = b1;  C = h2;   K = HID; ldc = HID; relu = 1; }
    else                 { A = h2; Bt = W2t; bias = b2v; C = lgts; K = HID; ldc = LGN; relu = 0; }

    const u16* gA0 = A  + (bm + row0)      * (size_t)K + g_ * 8;
    const u16* gA1 = A  + (bm + row0 + 32) * (size_t)K + g_ * 8;
    const u16* gA2 = A  + (bm + row0 + 64) * (size_t)K + g_ * 8;
    const u16* gA3 = A  + (bm + row0 + 96) * (size_t)K + g_ * 8;
    const u16* gB0 = Bt + (bn + row0)      * (size_t)K + g_ * 8;
    const u16* gB1 = Bt + (bn + row0 + 32) * (size_t)K + g_ * 8;
    const u16* gB2 = Bt + (bn + row0 + 64) * (size_t)K + g_ * 8;
    const u16* gB3 = Bt + (bn + row0 + 96) * (size_t)K + g_ * 8;

    f32x4 acc[4][4] = {};

    auto issue = [&](int k0, int buf) {
      const int o = buf * 16384;
      async_cp16(gA0 + k0, lA + o);
      async_cp16(gA1 + k0, lA + o + 2048);
      async_cp16(gA2 + k0, lA + o + 4096);
      async_cp16(gA3 + k0, lA + o + 6144);
      async_cp16(gB0 + k0, lB + o);
      async_cp16(gB1 + k0, lB + o + 2048);
      async_cp16(gB2 + k0, lB + o + 4096);
      async_cp16(gB3 + k0, lB + o + 6144);
    };

    const int NIT = K / 64;
    issue(0, 0);
#pragma unroll 2
    for (int it = 0; it < NIT; ++it) {
      const int buf = it & 1;
      if (it + 1 < NIT) {
        issue((it + 1) * 64, buf ^ 1);
        asm volatile("s_waitcnt vmcnt(8)\n\ts_barrier" ::: "memory");
      } else {
        asm volatile("s_waitcnt vmcnt(0)\n\ts_barrier" ::: "memory");
      }

      const u16* qa = pa + buf * 16384;
      const u16* qb = pb + buf * 16384;
      bf16x8 af[4], bfr[4];
      // kk = 0 half (k 0..31 of the slab)
#pragma unroll
      for (int t = 0; t < 4; ++t) {
        af[t]  = *(const bf16x8*)(qa + t * 1024 + sk0);   // +16 rows * 64 stride
        bfr[t] = *(const bf16x8*)(qb + t * 1024 + sk0);
      }
#pragma unroll
      for (int tm = 0; tm < 4; ++tm)
#pragma unroll
        for (int tn = 0; tn < 4; ++tn)
          acc[tm][tn] = __builtin_amdgcn_mfma_f32_16x16x32_bf16(af[tm], bfr[tn], acc[tm][tn], 0, 0, 0);
      // kk = 1 half (k 32..63)
#pragma unroll
      for (int t = 0; t < 4; ++t) {
        af[t]  = *(const bf16x8*)(qa + t * 1024 + sk1);
        bfr[t] = *(const bf16x8*)(qb + t * 1024 + sk1);
      }
#pragma unroll
      for (int tm = 0; tm < 4; ++tm)
#pragma unroll
        for (int tn = 0; tn < 4; ++tn)
          acc[tm][tn] = __builtin_amdgcn_mfma_f32_16x16x32_bf16(af[tm], bfr[tn], acc[tm][tn], 0, 0, 0);

      asm volatile("s_waitcnt lgkmcnt(0)\n\ts_barrier" ::: "memory");
    }

    // epilogue: D row = lq*4 + r, col = lr (m89-verified layout)
#pragma unroll
    for (int tm = 0; tm < 4; ++tm) {
      size_t rw = bm + waveM * 64 + tm * 16 + lq * 4;
#pragma unroll
      for (int tn = 0; tn < 4; ++tn) {
        int col = (int)bn + waveN * 64 + tn * 16 + lr;
        float bv = bias[col];
#pragma unroll
        for (int r = 0; r < 4; ++r) {
          float v = acc[tm][tn][r] + bv;
          if (relu) v = fmaxf(v, 0.f);
          C[(rw + r) * (size_t)ldc + col] = f2bf(v);
        }
      }
    }

    if (layer < 2) grid_sync(gbar + layer);
  }
}

// ---------------- sampling (512 thr, grid 2048; 4 rows/block) --------------------
// 8 waves = 4 row-pairs x {R,S}. Single register-resident pass: each lane loads a
// 16B ushort8 chunk (8 cols) once; max, S, T all from registers. R wave: bulk cols
// 0..511 + lane0 extra col 512. S wave: bulk cols 512..1023 with col 512 masked
// out (lane0 elem0), extras x1024 (lane63) and x1025 (lane0) from the vectorized
// h2 x W2c dot. Verified math from r10 kept.
__global__ __launch_bounds__(512) void k_sample(const u16* __restrict__ lgts,
    const u16* __restrict__ h2, const u16* __restrict__ W2c,
    const float* __restrict__ b2,
    const int* __restrict__ idxR, const int* __restrict__ lenR,
    const int* __restrict__ idxS, const int* __restrict__ lenS,
    float* __restrict__ out) {
  __shared__ float shf[16];
  const int tid = threadIdx.x;
  const int w = tid >> 6, lane = tid & 63;
  const int grp = w & 1, pair = w >> 1;
  const int row = blockIdx.x * 4 + pair;
  const u16* base = lgts + (size_t)row * LGN + (grp ? NHEAD : 0);
  const int* sidx = (grp ? idxS : idxR) + (size_t)row * KSEL;
  const int slen  = (grp ? lenS : lenR)[row];

  float x1024 = 0.f, x1025 = 0.f;
  if (grp) {
    const bf16x8* hp  = (const bf16x8*)(h2 + (size_t)row * HID + lane * 16);
    const bf16x8* w0p = (const bf16x8*)(W2c + lane * 16);
    const bf16x8* w1p = (const bf16x8*)(W2c + 1024 + lane * 16);
    bf16x8 hv0 = hp[0],  hv1 = hp[1];
    bf16x8 a0  = w0p[0], a1  = w0p[1];
    bf16x8 c0  = w1p[0], c1  = w1p[1];
    float d0 = 0.f, d1 = 0.f;
#pragma unroll
    for (int j = 0; j < 8; ++j) {
      float h0 = bf2f((u16)hv0[j]);
      float h1 = bf2f((u16)hv1[j]);
      d0 += h0 * bf2f((u16)a0[j]) + h1 * bf2f((u16)a1[j]);
      d1 += h0 * bf2f((u16)c0[j]) + h1 * bf2f((u16)c1[j]);
    }
#pragma unroll
    for (int dd = 32; dd; dd >>= 1) { d0 += __shfl_xor(d0, dd, 64); d1 += __shfl_xor(d1, dd, 64); }
    x1024 = d0 + b2[1024];
    x1025 = d1 + b2[1025];
  }

  // bulk load: 8 cols/lane, one 16B load
  const u16* chunk = lgts + (size_t)row * LGN + (grp ? 512 : 0) + lane * 8;
  bf16x8 raw = *(const bf16x8*)chunk;
  float v[8];
#pragma unroll
  for (int j = 0; j < 8; ++j) v[j] = bf2f((u16)raw[j]);
  if (grp && lane == 0) v[0] = -3.4e38f;   // col 512 belongs to R

  // extra per-lane element (mirrors old lane assignment exactly)
  float xa = -3.4e38f; int has_xa = 0;
  if (!grp && lane == 0)  { xa = bf2f(base[512]); has_xa = 1; }  // R col 512
  if (grp  && lane == 63) { xa = x1024;           has_xa = 1; }
  if (grp  && lane == 0)  { xa = x1025;           has_xa = 1; }

  float m = -3.4e38f;
#pragma unroll
  for (int j = 0; j < 8; ++j) m = fmaxf(m, v[j]);
  if (has_xa) m = fmaxf(m, xa);
#pragma unroll
  for (int dd = 32; dd; dd >>= 1) m = fmaxf(m, __shfl_xor(m, dd, 64));

  float S = 0.f, T = 0.f;
#pragma unroll
  for (int j = 0; j < 8; ++j) {
    float e = __expf(v[j] - m);   // masked slots underflow to 0; 0*finite = 0
    S += e; T += e * v[j];
  }
  if (has_xa) { float e = __expf(xa - m); S += e; T += e * xa; }
#pragma unroll
  for (int dd = 32; dd; dd >>= 1) { S += __shfl_xor(S, dd, 64); T += __shfl_xor(T, dd, 64); }

  float e = 0.f, ex = 0.f, xt = 0.f;
  int active = (lane < KSEL) && (lane < slen);
  int valid = 0;
  if (active) {
    int id = sidx[lane];
    if (id >= 0) {
      valid = 1;
      if (grp && id >= 511) xt = (id == 511) ? x1024 : x1025;
      else                  xt = bf2f(base[id]);
      e  = __expf(xt - m);
      ex = e * xt;
    }
  }
  float pe = e, pex = ex;
#pragma unroll
  for (int dd = 1; dd < 32; dd <<= 1) {
    float qa = __shfl_up(pe, dd, 64);
    float qb = __shfl_up(pex, dd, 64);
    if (lane >= dd) { pe += qa; pex += qb; }
  }
  float lp = 0.f, en = 0.f;
  if (active) {
    float St = S - (pe - e);
    float Tt = T - (pex - ex);
    float logZ = m + __logf(St);
    en = logZ - Tt / St;
    if (valid) lp = xt - logZ;
  }
#pragma unroll
  for (int dd = 32; dd; dd >>= 1) { lp += __shfl_xor(lp, dd, 64); en += __shfl_xor(en, dd, 64); }

  if (lane == 0) { shf[w * 2] = lp; shf[w * 2 + 1] = en; }
  __syncthreads();
  if (lane == 0 && grp == 0) {
    out[row]         = shf[pair * 4] + shf[pair * 4 + 2];
    out[BATCH + row] = shf[pair * 4 + 1] + shf[pair * 4 + 3];
  }
}

// ---------------- launch ----------------
extern "C" void kernel_launch(void* const* d_in, const int* in_sizes, int n_in,
                              void* d_out, int out_size, void* d_ws, size_t ws_size,
                              hipStream_t stream) {
  (void)in_sizes; (void)n_in; (void)out_size; (void)ws_size;
  const float* state = (const float*)d_in[0];
  const float* W0 = (const float*)d_in[1];
  const float* b0 = (const float*)d_in[2];
  const float* W1 = (const float*)d_in[3];
  const float* b1 = (const float*)d_in[4];
  const float* W2 = (const float*)d_in[5];
  const float* b2 = (const float*)d_in[6];
  const int* idxR = (const int*)d_in[7];
  const int* lenR = (const int*)d_in[8];
  const int* idxS = (const int*)d_in[9];
  const int* lenS = (const int*)d_in[10];
  float* out = (float*)d_out;

  char* ws = (char*)d_ws;
  size_t off = 0;
  auto alloc = [&](size_t bytes) -> char* {
    char* p = ws + off;
    off = (off + bytes + 255) & ~(size_t)255;
    return p;
  };
  u16* As   = (u16*)alloc((size_t)BATCH * KP0 * 2);   // 17.8 MB
  u16* W0t  = (u16*)alloc((size_t)HID * KP0 * 2);     //  2.2 MB
  u16* W1t  = (u16*)alloc((size_t)HID * HID * 2);     //  2.1 MB
  u16* W2t  = (u16*)alloc((size_t)HID * LGN * 2);     //  2.1 MB
  u16* W2c  = (u16*)alloc((size_t)2 * 1024 * 2);      //  4 KB
  u16* h1   = (u16*)alloc((size_t)BATCH * HID * 2);   // 16.8 MB
  u16* h2   = (u16*)alloc((size_t)BATCH * HID * 2);   // 16.8 MB
  u16* lgts = (u16*)alloc((size_t)BATCH * LGN * 2);   // 16.8 MB
  unsigned* gbar = (unsigned*)alloc(256);             // grid-barrier counters

  k_cvt<<<4352, 512, 0, stream>>>(state, W0, W1, W2, As, W0t, W1t, W2t, W2c, gbar);

  k_mlp<<<GRIDM, 256, 0, stream>>>(As, W0t, b0, h1, W1t, b1, h2, W2t, b2, lgts, gbar);

  k_sample<<<2048, 512, 0, stream>>>(lgts, h2, W2c, b2, idxR, lenR, idxS, lenS, out);
}

// Round 5
// 216.476 us; speedup vs baseline: 1.6670x; 1.6670x over previous
//
#include <hip/hip_runtime.h>
#include <cstdint>
#include <cstddef>

#define BATCH 8192
#define DIN   1025
#define HID   1024
#define NACT  1026
#define NHEAD 513
#define KSEL  32
#define KP0   1088   /* DIN padded to multiple of 64 */
#define LGN   1024   /* logits cols 0..1023 via GEMM; 1024/1025 computed in sample */

typedef unsigned short u16;
typedef short bf16x8 __attribute__((ext_vector_type(8)));
typedef float f32x4 __attribute__((ext_vector_type(4)));

__device__ __forceinline__ u16 f2bf(float f) {
  unsigned u = __float_as_uint(f);
  u += 0x7fff + ((u >> 16) & 1);   // round-to-nearest-even
  return (u16)(u >> 16);
}
__device__ __forceinline__ float bf2f(u16 h) {
  return __uint_as_float((unsigned)h << 16);
}

__device__ __forceinline__ void async_cp16(const u16* g, u16* l) {
  __builtin_amdgcn_global_load_lds((const __attribute__((address_space(1))) void*)g,
                                   (__attribute__((address_space(3))) void*)l,
                                   16, 0, 0);
}

// ---------------- conversion kernel (512 thr, grid 4352) ----------------
// blocks: state cvt one pass (4352*512*4 = BATCH*KP0); blocks 0..3136 also do one
// 32x32 weight-transpose tile each (W0t 1088, W1t 1024, W2t 1024, W2c 1).
__global__ __launch_bounds__(512) void k_cvt(const float* __restrict__ state,
    const float* __restrict__ W0, const float* __restrict__ W1,
    const float* __restrict__ W2,
    u16* __restrict__ As, u16* __restrict__ W0t, u16* __restrict__ W1t,
    u16* __restrict__ W2t, u16* __restrict__ W2c) {
  const int tid = threadIdx.x;
  const int b = blockIdx.x;
  // state f32 [B][DIN] -> bf16 [B][KP0], 4 elems/thread
  {
    int i = b * 512 + tid;
    const int QPR = KP0 / 4;   // 272
    int r = i / QPR, c4 = (i - r * QPR) * 4;
    const float* src = state + (size_t)r * DIN + c4;
    ushort4 o;
    if (c4 + 3 < DIN) {
      o.x = f2bf(src[0]); o.y = f2bf(src[1]); o.z = f2bf(src[2]); o.w = f2bf(src[3]);
    } else {
      o.x = (c4 + 0 < DIN) ? f2bf(src[0]) : 0;
      o.y = (c4 + 1 < DIN) ? f2bf(src[1]) : 0;
      o.z = (c4 + 2 < DIN) ? f2bf(src[2]) : 0;
      o.w = (c4 + 3 < DIN) ? f2bf(src[3]) : 0;
    }
    *(ushort4*)(As + (size_t)r * KP0 + c4) = o;
  }
  if (b >= 3137) return;
  if (b == 3136) {   // W2 cols 1024,1025 -> W2c[2][1024]
    for (int e = tid; e < 2048; e += 512) {
      int j = e >> 10, k = e & 1023;
      W2c[e] = f2bf(W2[(size_t)k * NACT + 1024 + j]);
    }
    return;
  }
  const float* W; u16* Wt; int K, ldW, Kp, tt = b;
  if (tt < 1088)      { W = W0; Wt = W0t; K = DIN; ldW = HID;  Kp = KP0; }
  else if (tt < 2112) { tt -= 1088; W = W1; Wt = W1t; K = HID; ldW = HID;  Kp = HID; }
  else                { tt -= 2112; W = W2; Wt = W2t; K = HID; ldW = NACT; Kp = HID; }
  int n0 = (tt & 31) * 32, k0 = (tt >> 5) * 32;
  __shared__ float tile[32][33];
  const int tx = tid & 31, ty = tid >> 5;   // ty 0..15
#pragma unroll
  for (int i = 0; i < 32; i += 16) {
    int k = k0 + ty + i;
    tile[ty + i][tx] = (k < K) ? W[(size_t)k * ldW + n0 + tx] : 0.f;
  }
  __syncthreads();
#pragma unroll
  for (int i = 0; i < 32; i += 16)
    Wt[(size_t)(n0 + ty + i) * Kp + k0 + tx] = f2bf(tile[tx][ty + i]);
}

// ---- GEMM: m201-style 8-phase 256x256 tile, BK=64, 512 thr = 8 waves (2M x 4N,
// wave tile 128x64). grid 128 (32 mtiles x 4 ntiles), 1 block/CU (LDS 128KB).
// Per K-tile: 4 phases, each {ds_read subtile (8 or 4 x b128) | stage 4 x
// global_load_lds of next tile | barrier | lgkmcnt(0)+sched_barrier(0) (rule 18)
// | setprio(1) 16 MFMA setprio(0) (T5) | barrier}. Loads issued phases 0/1 stay
// in flight across 5 barriers; single vmcnt(0) per K-tile at phase 3 (by then
// ~2.5 phases of latency cover). T3+T4 per m196/m218: fine interleave + counted
// waits = +28-41% over the 2-phase loop; T5 +21-25% on top (m218b).
// Swizzle (HW-validated 0-conflict in r4 counters, rule 21 both-sides): chunk
// c -> row c>>3, slot c&7, global kchunk g = slot^(row&7); LDS dest linear;
// ds_read slot = (kk*4+lq)^(lr&7). Accumulation order per element identical to
// r3 (kk0 then kk1) -> same numerics.
template<bool RELU, int K>
__global__ __launch_bounds__(512, 2)
void gemm256(const u16* __restrict__ A, const u16* __restrict__ Bt,
             const float* __restrict__ bias, u16* __restrict__ Cout, int ldc)
{
  __shared__ __align__(16) u16 lds[65536];   // 2 bufs x (A 16K u16 + B 16K u16) = 128 KB

  const int d = blockIdx.x;
  // XCD swizzle, bijective (grid 128 = 16/XCD): each XCD owns 4 mtiles x all 4
  // ntiles -> A band 2MB + B panel 2MB ~ L2-resident per XCD.
  const int wg    = (d & 7) * 16 + (d >> 3);
  const int mtile = wg >> 2;          // 0..31
  const int ntile = wg & 3;           // 0..3
  const size_t bm = (size_t)mtile * 256;
  const size_t bn = (size_t)ntile * 256;

  const int tid  = threadIdx.x;
  const int wave = tid >> 6;
  const int lane = tid & 63;
  const int waveM = wave >> 2, waveN = wave & 3;   // 2M x 4N
  const int lr = lane & 15, lq = lane >> 4;
  const int xr = lr & 7;

  // staging: per matrix 2048 chunks of 16B; thread t, sub-load k: chunk
  // c = t + 512k -> row = (t>>3)+64k, slot = t&7, g = slot^(row&7) (const/thread).
  const int row0 = tid >> 3;                       // 0..63
  const int g_   = (tid & 7) ^ ((tid >> 3) & 7);
  const u16* gA0 = A  + (bm + row0)       * (size_t)K + g_ * 8;
  const u16* gA1 = A  + (bm + row0 + 64)  * (size_t)K + g_ * 8;
  const u16* gA2 = A  + (bm + row0 + 128) * (size_t)K + g_ * 8;
  const u16* gA3 = A  + (bm + row0 + 192) * (size_t)K + g_ * 8;
  const u16* gB0 = Bt + (bn + row0)       * (size_t)K + g_ * 8;
  const u16* gB1 = Bt + (bn + row0 + 64)  * (size_t)K + g_ * 8;
  const u16* gB2 = Bt + (bn + row0 + 128) * (size_t)K + g_ * 8;
  const u16* gB3 = Bt + (bn + row0 + 192) * (size_t)K + g_ * 8;
  // per-wave uniform LDS staging bases (u16 offsets): chunk c at c*8
  u16* lA = lds + wave * 512;            // + 4096*k ; +16384 for B; +bufo
  u16* lB = lds + 16384 + wave * 512;

  // fragment read bases: A frag (mf,kk) at paA + bufo + mf*1024 + s(kk);
  // B frag (nf,kk) at paB + bufo + nf*1024 + s(kk). row&7 = lr&7 = xr.
  const u16* paA = lds + (waveM * 128 + lr) * 64;
  const u16* paB = lds + 16384 + (waveN * 64 + lr) * 64;
  const int s0 = ( lq      ^ xr) * 8;   // kk=0 slot (u16 off)
  const int s1 = ((4 | lq) ^ xr) * 8;   // kk=1

  f32x4 acc[8][4] = {};
  bf16x8 af[4], ag[4], bfr[4], bgr[4];

  // prologue: stage K-tile 0 into buf0, drain, barrier
  {
    async_cp16(gA0, lA);            async_cp16(gA1, lA + 4096);
    async_cp16(gA2, lA + 8192);     async_cp16(gA3, lA + 12288);
    async_cp16(gB0, lB);            async_cp16(gB1, lB + 4096);
    async_cp16(gB2, lB + 8192);     async_cp16(gB3, lB + 12288);
    asm volatile("s_waitcnt vmcnt(0)" ::: "memory");
    __builtin_amdgcn_s_barrier();
  }

  const int NIT = K / 64;
#pragma unroll 2
  for (int it = 0; it < NIT; ++it) {
    const int bo  = (it & 1) ? 32768 : 0;
    const int bo2 = 32768 - bo;
    const int kn  = (it + 1) * 64;
    const bool pf = (it + 1 < NIT);

    // ---- phase 0: B(kk0) + A(kk0) mf0-3 ; stage next-tile A ----
#pragma unroll
    for (int nf = 0; nf < 4; ++nf) bfr[nf] = *(const bf16x8*)(paB + bo + nf * 1024 + s0);
#pragma unroll
    for (int mf = 0; mf < 4; ++mf) af[mf]  = *(const bf16x8*)(paA + bo + mf * 1024 + s0);
    if (pf) {
      async_cp16(gA0 + kn, lA + bo2);         async_cp16(gA1 + kn, lA + bo2 + 4096);
      async_cp16(gA2 + kn, lA + bo2 + 8192);  async_cp16(gA3 + kn, lA + bo2 + 12288);
    }
    __builtin_amdgcn_s_barrier();
    asm volatile("s_waitcnt lgkmcnt(0)" ::: "memory");
    __builtin_amdgcn_sched_barrier(0);
    __builtin_amdgcn_s_setprio(1);
#pragma unroll
    for (int mf = 0; mf < 4; ++mf)
#pragma unroll
      for (int nf = 0; nf < 4; ++nf)
        acc[mf][nf] = __builtin_amdgcn_mfma_f32_16x16x32_bf16(af[mf], bfr[nf], acc[mf][nf], 0, 0, 0);
    __builtin_amdgcn_s_setprio(0);
    __builtin_amdgcn_s_barrier();

    // ---- phase 1: A(kk0) mf4-7 ; stage next-tile B ----
#pragma unroll
    for (int mf = 0; mf < 4; ++mf) ag[mf] = *(const bf16x8*)(paA + bo + (mf + 4) * 1024 + s0);
    if (pf) {
      async_cp16(gB0 + kn, lB + bo2);         async_cp16(gB1 + kn, lB + bo2 + 4096);
      async_cp16(gB2 + kn, lB + bo2 + 8192);  async_cp16(gB3 + kn, lB + bo2 + 12288);
    }
    __builtin_amdgcn_s_barrier();
    asm volatile("s_waitcnt lgkmcnt(0)" ::: "memory");
    __builtin_amdgcn_sched_barrier(0);
    __builtin_amdgcn_s_setprio(1);
#pragma unroll
    for (int mf = 0; mf < 4; ++mf)
#pragma unroll
      for (int nf = 0; nf < 4; ++nf)
        acc[mf + 4][nf] = __builtin_amdgcn_mfma_f32_16x16x32_bf16(ag[mf], bfr[nf], acc[mf + 4][nf], 0, 0, 0);
    __builtin_amdgcn_s_setprio(0);
    __builtin_amdgcn_s_barrier();

    // ---- phase 2: B(kk1) + A(kk1) mf0-3 ----
#pragma unroll
    for (int nf = 0; nf < 4; ++nf) bgr[nf] = *(const bf16x8*)(paB + bo + nf * 1024 + s1);
#pragma unroll
    for (int mf = 0; mf < 4; ++mf) af[mf]  = *(const bf16x8*)(paA + bo + mf * 1024 + s1);
    __builtin_amdgcn_s_barrier();
    asm volatile("s_waitcnt lgkmcnt(0)" ::: "memory");
    __builtin_amdgcn_sched_barrier(0);
    __builtin_amdgcn_s_setprio(1);
#pragma unroll
    for (int mf = 0; mf < 4; ++mf)
#pragma unroll
      for (int nf = 0; nf < 4; ++nf)
        acc[mf][nf] = __builtin_amdgcn_mfma_f32_16x16x32_bf16(af[mf], bgr[nf], acc[mf][nf], 0, 0, 0);
    __builtin_amdgcn_s_setprio(0);
    __builtin_amdgcn_s_barrier();

    // ---- phase 3: A(kk1) mf4-7 ; close K-tile (single vmcnt drain) ----
#pragma unroll
    for (int mf = 0; mf < 4; ++mf) ag[mf] = *(const bf16x8*)(paA + bo + (mf + 4) * 1024 + s1);
    __builtin_amdgcn_s_barrier();
    asm volatile("s_waitcnt lgkmcnt(0)" ::: "memory");
    __builtin_amdgcn_sched_barrier(0);
    __builtin_amdgcn_s_setprio(1);
#pragma unroll
    for (int mf = 0; mf < 4; ++mf)
#pragma unroll
      for (int nf = 0; nf < 4; ++nf)
        acc[mf + 4][nf] = __builtin_amdgcn_mfma_f32_16x16x32_bf16(ag[mf], bgr[nf], acc[mf + 4][nf], 0, 0, 0);
    __builtin_amdgcn_s_setprio(0);
    if (pf) asm volatile("s_waitcnt vmcnt(0)" ::: "memory");
    __builtin_amdgcn_s_barrier();
  }

  // epilogue: D row = lq*4 + r, col = lr (m89-verified layout)
#pragma unroll
  for (int mf = 0; mf < 8; ++mf) {
    size_t rw = bm + waveM * 128 + mf * 16 + lq * 4;
#pragma unroll
    for (int nf = 0; nf < 4; ++nf) {
      int col = (int)bn + waveN * 64 + nf * 16 + lr;
      float bv = bias[col];
#pragma unroll
      for (int r = 0; r < 4; ++r) {
        float v = acc[mf][nf][r] + bv;
        if (RELU) v = fmaxf(v, 0.f);
        Cout[(rw + r) * (size_t)ldc + col] = f2bf(v);
      }
    }
  }
}

// ---------------- sampling (512 thr, grid 2048; 4 rows/block) --------------------
// 8 waves = 4 row-pairs x {R,S}. Single register-resident pass: each lane loads a
// 16B ushort8 chunk (8 cols) once; max, S, T all from registers. R wave: bulk cols
// 0..511 + lane0 extra col 512. S wave: bulk cols 512..1023 with col 512 masked
// out (lane0 elem0), extras x1024 (lane63) and x1025 (lane0) from the vectorized
// h2 x W2c dot. Verified math kept.
__global__ __launch_bounds__(512) void k_sample(const u16* __restrict__ lgts,
    const u16* __restrict__ h2, const u16* __restrict__ W2c,
    const float* __restrict__ b2,
    const int* __restrict__ idxR, const int* __restrict__ lenR,
    const int* __restrict__ idxS, const int* __restrict__ lenS,
    float* __restrict__ out) {
  __shared__ float shf[16];
  const int tid = threadIdx.x;
  const int w = tid >> 6, lane = tid & 63;
  const int grp = w & 1, pair = w >> 1;
  const int row = blockIdx.x * 4 + pair;
  const u16* base = lgts + (size_t)row * LGN + (grp ? NHEAD : 0);
  const int* sidx = (grp ? idxS : idxR) + (size_t)row * KSEL;
  const int slen  = (grp ? lenS : lenR)[row];

  float x1024 = 0.f, x1025 = 0.f;
  if (grp) {
    const bf16x8* hp  = (const bf16x8*)(h2 + (size_t)row * HID + lane * 16);
    const bf16x8* w0p = (const bf16x8*)(W2c + lane * 16);
    const bf16x8* w1p = (const bf16x8*)(W2c + 1024 + lane * 16);
    bf16x8 hv0 = hp[0],  hv1 = hp[1];
    bf16x8 a0  = w0p[0], a1  = w0p[1];
    bf16x8 c0  = w1p[0], c1  = w1p[1];
    float d0 = 0.f, d1 = 0.f;
#pragma unroll
    for (int j = 0; j < 8; ++j) {
      float h0 = bf2f((u16)hv0[j]);
      float h1 = bf2f((u16)hv1[j]);
      d0 += h0 * bf2f((u16)a0[j]) + h1 * bf2f((u16)a1[j]);
      d1 += h0 * bf2f((u16)c0[j]) + h1 * bf2f((u16)c1[j]);
    }
#pragma unroll
    for (int dd = 32; dd; dd >>= 1) { d0 += __shfl_xor(d0, dd, 64); d1 += __shfl_xor(d1, dd, 64); }
    x1024 = d0 + b2[1024];
    x1025 = d1 + b2[1025];
  }

  // bulk load: 8 cols/lane, one 16B load
  const u16* chunk = lgts + (size_t)row * LGN + (grp ? 512 : 0) + lane * 8;
  bf16x8 raw = *(const bf16x8*)chunk;
  float v[8];
#pragma unroll
  for (int j = 0; j < 8; ++j) v[j] = bf2f((u16)raw[j]);
  if (grp && lane == 0) v[0] = -3.4e38f;   // col 512 belongs to R

  // extra per-lane element (mirrors old lane assignment exactly)
  float xa = -3.4e38f; int has_xa = 0;
  if (!grp && lane == 0)  { xa = bf2f(base[512]); has_xa = 1; }  // R col 512
  if (grp  && lane == 63) { xa = x1024;           has_xa = 1; }
  if (grp  && lane == 0)  { xa = x1025;           has_xa = 1; }

  float m = -3.4e38f;
#pragma unroll
  for (int j = 0; j < 8; ++j) m = fmaxf(m, v[j]);
  if (has_xa) m = fmaxf(m, xa);
#pragma unroll
  for (int dd = 32; dd; dd >>= 1) m = fmaxf(m, __shfl_xor(m, dd, 64));

  float S = 0.f, T = 0.f;
#pragma unroll
  for (int j = 0; j < 8; ++j) {
    float e = __expf(v[j] - m);   // masked slots underflow to 0; 0*finite = 0
    S += e; T += e * v[j];
  }
  if (has_xa) { float e = __expf(xa - m); S += e; T += e * xa; }
#pragma unroll
  for (int dd = 32; dd; dd >>= 1) { S += __shfl_xor(S, dd, 64); T += __shfl_xor(T, dd, 64); }

  float e = 0.f, ex = 0.f, xt = 0.f;
  int active = (lane < KSEL) && (lane < slen);
  int valid = 0;
  if (active) {
    int id = sidx[lane];
    if (id >= 0) {
      valid = 1;
      if (grp && id >= 511) xt = (id == 511) ? x1024 : x1025;
      else                  xt = bf2f(base[id]);
      e  = __expf(xt - m);
      ex = e * xt;
    }
  }
  float pe = e, pex = ex;
#pragma unroll
  for (int dd = 1; dd < 32; dd <<= 1) {
    float qa = __shfl_up(pe, dd, 64);
    float qb = __shfl_up(pex, dd, 64);
    if (lane >= dd) { pe += qa; pex += qb; }
  }
  float lp = 0.f, en = 0.f;
  if (active) {
    float St = S - (pe - e);
    float Tt = T - (pex - ex);
    float logZ = m + __logf(St);
    en = logZ - Tt / St;
    if (valid) lp = xt - logZ;
  }
#pragma unroll
  for (int dd = 32; dd; dd >>= 1) { lp += __shfl_xor(lp, dd, 64); en += __shfl_xor(en, dd, 64); }

  if (lane == 0) { shf[w * 2] = lp; shf[w * 2 + 1] = en; }
  __syncthreads();
  if (lane == 0 && grp == 0) {
    out[row]         = shf[pair * 4] + shf[pair * 4 + 2];
    out[BATCH + row] = shf[pair * 4 + 1] + shf[pair * 4 + 3];
  }
}

// ---------------- launch ----------------
extern "C" void kernel_launch(void* const* d_in, const int* in_sizes, int n_in,
                              void* d_out, int out_size, void* d_ws, size_t ws_size,
                              hipStream_t stream) {
  (void)in_sizes; (void)n_in; (void)out_size; (void)ws_size;
  const float* state = (const float*)d_in[0];
  const float* W0 = (const float*)d_in[1];
  const float* b0 = (const float*)d_in[2];
  const float* W1 = (const float*)d_in[3];
  const float* b1 = (const float*)d_in[4];
  const float* W2 = (const float*)d_in[5];
  const float* b2 = (const float*)d_in[6];
  const int* idxR = (const int*)d_in[7];
  const int* lenR = (const int*)d_in[8];
  const int* idxS = (const int*)d_in[9];
  const int* lenS = (const int*)d_in[10];
  float* out = (float*)d_out;

  char* ws = (char*)d_ws;
  size_t off = 0;
  auto alloc = [&](size_t bytes) -> char* {
    char* p = ws + off;
    off = (off + bytes + 255) & ~(size_t)255;
    return p;
  };
  u16* As   = (u16*)alloc((size_t)BATCH * KP0 * 2);   // 17.8 MB
  u16* W0t  = (u16*)alloc((size_t)HID * KP0 * 2);     //  2.2 MB
  u16* W1t  = (u16*)alloc((size_t)HID * HID * 2);     //  2.1 MB
  u16* W2t  = (u16*)alloc((size_t)HID * LGN * 2);     //  2.1 MB
  u16* W2c  = (u16*)alloc((size_t)2 * 1024 * 2);      //  4 KB
  u16* h1   = (u16*)alloc((size_t)BATCH * HID * 2);   // 16.8 MB
  u16* h2   = (u16*)alloc((size_t)BATCH * HID * 2);   // 16.8 MB
  u16* lgts = (u16*)alloc((size_t)BATCH * LGN * 2);   // 16.8 MB

  k_cvt<<<4352, 512, 0, stream>>>(state, W0, W1, W2, As, W0t, W1t, W2t, W2c);

  gemm256<true,  KP0><<<128, 512, 0, stream>>>(As, W0t, b0, h1,   HID);
  gemm256<true,  HID><<<128, 512, 0, stream>>>(h1, W1t, b1, h2,   HID);
  gemm256<false, HID><<<128, 512, 0, stream>>>(h2, W2t, b2, lgts, LGN);

  k_sample<<<2048, 512, 0, stream>>>(lgts, h2, W2c, b2, idxR, lenR, idxS, lenS, out);
}

// Round 6
// 185.045 us; speedup vs baseline: 1.9502x; 1.1699x over previous
//
#include <hip/hip_runtime.h>
#include <cstdint>
#include <cstddef>

#define BATCH 8192
#define DIN   1025
#define HID   1024
#define NACT  1026
#define NHEAD 513
#define KSEL  32
#define KP0   1088   /* DIN padded to multiple of 64 */
#define LGN   1024   /* logits cols 0..1023 via GEMM; 1024/1025 computed in sample */

typedef unsigned short u16;
typedef short bf16x8 __attribute__((ext_vector_type(8)));
typedef float f32x4 __attribute__((ext_vector_type(4)));

__device__ __forceinline__ u16 f2bf(float f) {
  unsigned u = __float_as_uint(f);
  u += 0x7fff + ((u >> 16) & 1);   // round-to-nearest-even
  return (u16)(u >> 16);
}
__device__ __forceinline__ float bf2f(u16 h) {
  return __uint_as_float((unsigned)h << 16);
}

__device__ __forceinline__ void async_cp16(const u16* g, u16* l) {
  __builtin_amdgcn_global_load_lds((const __attribute__((address_space(1))) void*)g,
                                   (__attribute__((address_space(3))) void*)l,
                                   16, 0, 0);
}

// ---------------- conversion kernel (512 thr, grid 4352) ----------------
// blocks: state cvt one pass (4352*512*4 = BATCH*KP0); blocks 0..3136 also do one
// 32x32 weight-transpose tile each (W0t 1088, W1t 1024, W2t 1024, W2c 1).
__global__ __launch_bounds__(512) void k_cvt(const float* __restrict__ state,
    const float* __restrict__ W0, const float* __restrict__ W1,
    const float* __restrict__ W2,
    u16* __restrict__ As, u16* __restrict__ W0t, u16* __restrict__ W1t,
    u16* __restrict__ W2t, u16* __restrict__ W2c) {
  const int tid = threadIdx.x;
  const int b = blockIdx.x;
  // state f32 [B][DIN] -> bf16 [B][KP0], 4 elems/thread
  {
    int i = b * 512 + tid;
    const int QPR = KP0 / 4;   // 272
    int r = i / QPR, c4 = (i - r * QPR) * 4;
    const float* src = state + (size_t)r * DIN + c4;
    ushort4 o;
    if (c4 + 3 < DIN) {
      o.x = f2bf(src[0]); o.y = f2bf(src[1]); o.z = f2bf(src[2]); o.w = f2bf(src[3]);
    } else {
      o.x = (c4 + 0 < DIN) ? f2bf(src[0]) : 0;
      o.y = (c4 + 1 < DIN) ? f2bf(src[1]) : 0;
      o.z = (c4 + 2 < DIN) ? f2bf(src[2]) : 0;
      o.w = (c4 + 3 < DIN) ? f2bf(src[3]) : 0;
    }
    *(ushort4*)(As + (size_t)r * KP0 + c4) = o;
  }
  if (b >= 3137) return;
  if (b == 3136) {   // W2 cols 1024,1025 -> W2c[2][1024]
    for (int e = tid; e < 2048; e += 512) {
      int j = e >> 10, k = e & 1023;
      W2c[e] = f2bf(W2[(size_t)k * NACT + 1024 + j]);
    }
    return;
  }
  const float* W; u16* Wt; int K, ldW, Kp, tt = b;
  if (tt < 1088)      { W = W0; Wt = W0t; K = DIN; ldW = HID;  Kp = KP0; }
  else if (tt < 2112) { tt -= 1088; W = W1; Wt = W1t; K = HID; ldW = HID;  Kp = HID; }
  else                { tt -= 2112; W = W2; Wt = W2t; K = HID; ldW = NACT; Kp = HID; }
  int n0 = (tt & 31) * 32, k0 = (tt >> 5) * 32;
  __shared__ float tile[32][33];
  const int tx = tid & 31, ty = tid >> 5;   // ty 0..15
#pragma unroll
  for (int i = 0; i < 32; i += 16) {
    int k = k0 + ty + i;
    tile[ty + i][tx] = (k < K) ? W[(size_t)k * ldW + n0 + tx] : 0.f;
  }
  __syncthreads();
#pragma unroll
  for (int i = 0; i < 32; i += 16)
    Wt[(size_t)(n0 + ty + i) * Kp + k0 + tx] = f2bf(tile[tx][ty + i]);
}

// ---- GEMM: 8-phase-style 256x128 tile, BK=64, 512 thr = 8 waves (4M x 2N,
// wave tile 64x64, acc[4][4], 16 MFMA/phase -- m201 granularity). grid 256
// (32 mtiles x 8 ntiles) = 1 block/CU on ALL 256 CUs (r5 post-mortem: 8-phase
// doubled per-CU rate to ~3.5 TF/CU but 128-block grid idled half the chip).
// TRUE T4 counted-vmcnt: 3-deep LDS (3 x 48 KB = 144 KB), prefetch 2 K-tiles
// ahead, steady-state s_waitcnt vmcnt(6) at tile end (never 0 until the tail)
// -- per-tile in-flight ledger: after issuing t+2, in-flight = 6(t+1)+6(t+2);
// vmcnt(6) drains exactly t+1 before tile t+1 reads it. Tail: t=NIT-2 ->
// vmcnt(0); t=NIT-1 -> none. Phase body retained verbatim from r5 (passed
// correctness): [ds_read 8 x b128 | stage] barrier; lgkmcnt(0);
// sched_barrier(0) (rule 18); setprio(1) 16 MFMA setprio(0) (T5); barrier.
// Swizzle (HW-validated 0-conflict, rule 21 both-sides): chunk c -> row c>>3,
// slot c&7, global kchunk g = slot^(row&7); LDS linear; read slot
// (kk*4+lq)^(lr&7). Accumulation per element kk0-then-kk1 = r3/r5 numerics.
template<bool RELU, int K>
__global__ __launch_bounds__(512, 1)
void gemm_bt(const u16* __restrict__ A, const u16* __restrict__ Bt,
             const float* __restrict__ bias, u16* __restrict__ Cout, int ldc)
{
  __shared__ __align__(16) u16 lds[73728];   // 3 bufs x (A 16K u16 + B 8K u16) = 144 KB

  const int d = blockIdx.x;
  // XCD swizzle, bijective (grid 256 = 32/XCD): each XCD owns 4 consecutive
  // mtiles x all 8 ntiles -> A band 2.2 MB + B panel 2.2 MB ~ L2-resident.
  const int wg    = (d & 7) * 32 + (d >> 3);
  const int mtile = wg >> 3;          // 0..31
  const int ntile = wg & 7;           // 0..7
  const size_t bm = (size_t)mtile * 256;
  const size_t bn = (size_t)ntile * 128;

  const int tid  = threadIdx.x;
  const int wave = tid >> 6;
  const int lane = tid & 63;
  const int waveM = wave >> 1, waveN = wave & 1;   // 4M x 2N, 64x64 each
  const int lr = lane & 15, lq = lane >> 4;
  const int xr = lr & 7;

  // staging: A 2048 chunks (4 loads/thread), B 1024 chunks (2 loads/thread);
  // chunk c = tid + 512k -> row (tid>>3)+64k, slot tid&7, g = slot^(row&7)
  // constant per thread (64k = 0 mod 8).
  const int row0 = tid >> 3;                       // 0..63
  const int g_   = (tid & 7) ^ ((tid >> 3) & 7);
  const u16* gA0 = A  + (bm + row0)       * (size_t)K + g_ * 8;
  const u16* gA1 = A  + (bm + row0 + 64)  * (size_t)K + g_ * 8;
  const u16* gA2 = A  + (bm + row0 + 128) * (size_t)K + g_ * 8;
  const u16* gA3 = A  + (bm + row0 + 192) * (size_t)K + g_ * 8;
  const u16* gB0 = Bt + (bn + row0)       * (size_t)K + g_ * 8;
  const u16* gB1 = Bt + (bn + row0 + 64)  * (size_t)K + g_ * 8;

  auto stage = [&](int k0, int wb) {
    u16* a = lds + wb * 24576 + wave * 512;   // wave-uniform base + lane*16B
    u16* b = a + 16384;
    async_cp16(gA0 + k0, a);
    async_cp16(gA1 + k0, a + 4096);
    async_cp16(gA2 + k0, a + 8192);
    async_cp16(gA3 + k0, a + 12288);
    async_cp16(gB0 + k0, b);
    async_cp16(gB1 + k0, b + 4096);
  };

  // fragment read bases (per-buf offset added in loop): A row = waveM*64 +
  // mf*16 + lr (0..255), B row = waveN*64 + nf*16 + lr (0..127); row stride
  // 64 u16; slot s(kk) = (kk*4+lq)^xr.
  const int offA = (waveM * 64 + lr) * 64;
  const int offB = 16384 + (waveN * 64 + lr) * 64;
  const int s0 = ( lq      ^ xr) * 8;
  const int s1 = ((4 | lq) ^ xr) * 8;

  f32x4 acc[4][4] = {};
  bf16x8 af[4], bfr[4];

  const int NIT = K / 64;
  // prologue: stage tiles 0,1 into bufs 0,1; drain tile 0 (vmcnt(6) leaves
  // tile 1's 6 loads in flight); barrier.
  stage(0, 0);
  stage(64, 1);
  asm volatile("s_waitcnt vmcnt(6)" ::: "memory");
  __builtin_amdgcn_s_barrier();

  int rb = 0;   // buf holding tile t
  for (int t = 0; t < NIT; ++t) {
    const int ro = rb * 24576;
    const bool pf = (t + 2 < NIT);

    // ---- phase 0 (kk0): 8 ds_read ; stage tile t+2 ----
#pragma unroll
    for (int nf = 0; nf < 4; ++nf) bfr[nf] = *(const bf16x8*)(lds + ro + offB + nf * 1024 + s0);
#pragma unroll
    for (int mf = 0; mf < 4; ++mf) af[mf]  = *(const bf16x8*)(lds + ro + offA + mf * 1024 + s0);
    if (pf) {
      int wb = rb - 1; if (wb < 0) wb = 2;   // (rb+2)%3
      stage((t + 2) * 64, wb);
    }
    __builtin_amdgcn_s_barrier();
    asm volatile("s_waitcnt lgkmcnt(0)" ::: "memory");
    __builtin_amdgcn_sched_barrier(0);
    __builtin_amdgcn_s_setprio(1);
#pragma unroll
    for (int mf = 0; mf < 4; ++mf)
#pragma unroll
      for (int nf = 0; nf < 4; ++nf)
        acc[mf][nf] = __builtin_amdgcn_mfma_f32_16x16x32_bf16(af[mf], bfr[nf], acc[mf][nf], 0, 0, 0);
    __builtin_amdgcn_s_setprio(0);
    __builtin_amdgcn_s_barrier();

    // ---- phase 1 (kk1): 8 ds_read ; counted tile-end wait ----
#pragma unroll
    for (int nf = 0; nf < 4; ++nf) bfr[nf] = *(const bf16x8*)(lds + ro + offB + nf * 1024 + s1);
#pragma unroll
    for (int mf = 0; mf < 4; ++mf) af[mf]  = *(const bf16x8*)(lds + ro + offA + mf * 1024 + s1);
    __builtin_amdgcn_s_barrier();
    asm volatile("s_waitcnt lgkmcnt(0)" ::: "memory");
    __builtin_amdgcn_sched_barrier(0);
    __builtin_amdgcn_s_setprio(1);
#pragma unroll
    for (int mf = 0; mf < 4; ++mf)
#pragma unroll
      for (int nf = 0; nf < 4; ++nf)
        acc[mf][nf] = __builtin_amdgcn_mfma_f32_16x16x32_bf16(af[mf], bfr[nf], acc[mf][nf], 0, 0, 0);
    __builtin_amdgcn_s_setprio(0);
    if (pf)               asm volatile("s_waitcnt vmcnt(6)" ::: "memory");
    else if (t + 1 < NIT) asm volatile("s_waitcnt vmcnt(0)" ::: "memory");
    __builtin_amdgcn_s_barrier();

    rb = (rb == 2) ? 0 : rb + 1;
  }

  // epilogue: D row = lq*4 + r, col = lr (m89-verified layout)
#pragma unroll
  for (int mf = 0; mf < 4; ++mf) {
    size_t rw = bm + waveM * 64 + mf * 16 + lq * 4;
#pragma unroll
    for (int nf = 0; nf < 4; ++nf) {
      int col = (int)bn + waveN * 64 + nf * 16 + lr;
      float bv = bias[col];
#pragma unroll
      for (int r = 0; r < 4; ++r) {
        float v = acc[mf][nf][r] + bv;
        if (RELU) v = fmaxf(v, 0.f);
        Cout[(rw + r) * (size_t)ldc + col] = f2bf(v);
      }
    }
  }
}

// ---------------- sampling (512 thr, grid 2048; 4 rows/block) --------------------
// 8 waves = 4 row-pairs x {R,S}. Single register-resident pass: each lane loads a
// 16B ushort8 chunk (8 cols) once; max, S, T all from registers. R wave: bulk cols
// 0..511 + lane0 extra col 512. S wave: bulk cols 512..1023 with col 512 masked
// out (lane0 elem0), extras x1024 (lane63) and x1025 (lane0) from the vectorized
// h2 x W2c dot. Verified math kept.
__global__ __launch_bounds__(512) void k_sample(const u16* __restrict__ lgts,
    const u16* __restrict__ h2, const u16* __restrict__ W2c,
    const float* __restrict__ b2,
    const int* __restrict__ idxR, const int* __restrict__ lenR,
    const int* __restrict__ idxS, const int* __restrict__ lenS,
    float* __restrict__ out) {
  __shared__ float shf[16];
  const int tid = threadIdx.x;
  const int w = tid >> 6, lane = tid & 63;
  const int grp = w & 1, pair = w >> 1;
  const int row = blockIdx.x * 4 + pair;
  const u16* base = lgts + (size_t)row * LGN + (grp ? NHEAD : 0);
  const int* sidx = (grp ? idxS : idxR) + (size_t)row * KSEL;
  const int slen  = (grp ? lenS : lenR)[row];

  float x1024 = 0.f, x1025 = 0.f;
  if (grp) {
    const bf16x8* hp  = (const bf16x8*)(h2 + (size_t)row * HID + lane * 16);
    const bf16x8* w0p = (const bf16x8*)(W2c + lane * 16);
    const bf16x8* w1p = (const bf16x8*)(W2c + 1024 + lane * 16);
    bf16x8 hv0 = hp[0],  hv1 = hp[1];
    bf16x8 a0  = w0p[0], a1  = w0p[1];
    bf16x8 c0  = w1p[0], c1  = w1p[1];
    float d0 = 0.f, d1 = 0.f;
#pragma unroll
    for (int j = 0; j < 8; ++j) {
      float h0 = bf2f((u16)hv0[j]);
      float h1 = bf2f((u16)hv1[j]);
      d0 += h0 * bf2f((u16)a0[j]) + h1 * bf2f((u16)a1[j]);
      d1 += h0 * bf2f((u16)c0[j]) + h1 * bf2f((u16)c1[j]);
    }
#pragma unroll
    for (int dd = 32; dd; dd >>= 1) { d0 += __shfl_xor(d0, dd, 64); d1 += __shfl_xor(d1, dd, 64); }
    x1024 = d0 + b2[1024];
    x1025 = d1 + b2[1025];
  }

  // bulk load: 8 cols/lane, one 16B load
  const u16* chunk = lgts + (size_t)row * LGN + (grp ? 512 : 0) + lane * 8;
  bf16x8 raw = *(const bf16x8*)chunk;
  float v[8];
#pragma unroll
  for (int j = 0; j < 8; ++j) v[j] = bf2f((u16)raw[j]);
  if (grp && lane == 0) v[0] = -3.4e38f;   // col 512 belongs to R

  // extra per-lane element (mirrors old lane assignment exactly)
  float xa = -3.4e38f; int has_xa = 0;
  if (!grp && lane == 0)  { xa = bf2f(base[512]); has_xa = 1; }  // R col 512
  if (grp  && lane == 63) { xa = x1024;           has_xa = 1; }
  if (grp  && lane == 0)  { xa = x1025;           has_xa = 1; }

  float m = -3.4e38f;
#pragma unroll
  for (int j = 0; j < 8; ++j) m = fmaxf(m, v[j]);
  if (has_xa) m = fmaxf(m, xa);
#pragma unroll
  for (int dd = 32; dd; dd >>= 1) m = fmaxf(m, __shfl_xor(m, dd, 64));

  float S = 0.f, T = 0.f;
#pragma unroll
  for (int j = 0; j < 8; ++j) {
    float e = __expf(v[j] - m);   // masked slots underflow to 0; 0*finite = 0
    S += e; T += e * v[j];
  }
  if (has_xa) { float e = __expf(xa - m); S += e; T += e * xa; }
#pragma unroll
  for (int dd = 32; dd; dd >>= 1) { S += __shfl_xor(S, dd, 64); T += __shfl_xor(T, dd, 64); }

  float e = 0.f, ex = 0.f, xt = 0.f;
  int active = (lane < KSEL) && (lane < slen);
  int valid = 0;
  if (active) {
    int id = sidx[lane];
    if (id >= 0) {
      valid = 1;
      if (grp && id >= 511) xt = (id == 511) ? x1024 : x1025;
      else                  xt = bf2f(base[id]);
      e  = __expf(xt - m);
      ex = e * xt;
    }
  }
  float pe = e, pex = ex;
#pragma unroll
  for (int dd = 1; dd < 32; dd <<= 1) {
    float qa = __shfl_up(pe, dd, 64);
    float qb = __shfl_up(pex, dd, 64);
    if (lane >= dd) { pe += qa; pex += qb; }
  }
  float lp = 0.f, en = 0.f;
  if (active) {
    float St = S - (pe - e);
    float Tt = T - (pex - ex);
    float logZ = m + __logf(St);
    en = logZ - Tt / St;
    if (valid) lp = xt - logZ;
  }
#pragma unroll
  for (int dd = 32; dd; dd >>= 1) { lp += __shfl_xor(lp, dd, 64); en += __shfl_xor(en, dd, 64); }

  if (lane == 0) { shf[w * 2] = lp; shf[w * 2 + 1] = en; }
  __syncthreads();
  if (lane == 0 && grp == 0) {
    out[row]         = shf[pair * 4] + shf[pair * 4 + 2];
    out[BATCH + row] = shf[pair * 4 + 1] + shf[pair * 4 + 3];
  }
}

// ---------------- launch ----------------
extern "C" void kernel_launch(void* const* d_in, const int* in_sizes, int n_in,
                              void* d_out, int out_size, void* d_ws, size_t ws_size,
                              hipStream_t stream) {
  (void)in_sizes; (void)n_in; (void)out_size; (void)ws_size;
  const float* state = (const float*)d_in[0];
  const float* W0 = (const float*)d_in[1];
  const float* b0 = (const float*)d_in[2];
  const float* W1 = (const float*)d_in[3];
  const float* b1 = (const float*)d_in[4];
  const float* W2 = (const float*)d_in[5];
  const float* b2 = (const float*)d_in[6];
  const int* idxR = (const int*)d_in[7];
  const int* lenR = (const int*)d_in[8];
  const int* idxS = (const int*)d_in[9];
  const int* lenS = (const int*)d_in[10];
  float* out = (float*)d_out;

  char* ws = (char*)d_ws;
  size_t off = 0;
  auto alloc = [&](size_t bytes) -> char* {
    char* p = ws + off;
    off = (off + bytes + 255) & ~(size_t)255;
    return p;
  };
  u16* As   = (u16*)alloc((size_t)BATCH * KP0 * 2);   // 17.8 MB
  u16* W0t  = (u16*)alloc((size_t)HID * KP0 * 2);     //  2.2 MB
  u16* W1t  = (u16*)alloc((size_t)HID * HID * 2);     //  2.1 MB
  u16* W2t  = (u16*)alloc((size_t)HID * LGN * 2);     //  2.1 MB
  u16* W2c  = (u16*)alloc((size_t)2 * 1024 * 2);      //  4 KB
  u16* h1   = (u16*)alloc((size_t)BATCH * HID * 2);   // 16.8 MB
  u16* h2   = (u16*)alloc((size_t)BATCH * HID * 2);   // 16.8 MB
  u16* lgts = (u16*)alloc((size_t)BATCH * LGN * 2);   // 16.8 MB

  k_cvt<<<4352, 512, 0, stream>>>(state, W0, W1, W2, As, W0t, W1t, W2t, W2c);

  gemm_bt<true,  KP0><<<256, 512, 0, stream>>>(As, W0t, b0, h1,   HID);
  gemm_bt<true,  HID><<<256, 512, 0, stream>>>(h1, W1t, b1, h2,   HID);
  gemm_bt<false, HID><<<256, 512, 0, stream>>>(h2, W2t, b2, lgts, LGN);

  k_sample<<<2048, 512, 0, stream>>>(lgts, h2, W2c, b2, idxR, lenR, idxS, lenS, out);
}